// Round 4
// baseline (114.644 us; speedup 1.0000x reference)
//
#include <hip/hip_runtime.h>

#define NROWS 8192
#define NCENT 4096
#define DIM   256

#define AS1 __attribute__((address_space(1)))
#define AS3 __attribute__((address_space(3)))

typedef short bf16x8 __attribute__((ext_vector_type(8)));
typedef float f32x4  __attribute__((ext_vector_type(4)));

// fp32 -> bf16 round-to-nearest-even
__device__ inline unsigned short f2bf(float f) {
    unsigned u = __float_as_uint(f);
    return (unsigned short)((u + 0x7fffu + ((u >> 16) & 1u)) >> 16);
}

// ---------------------------------------------------------------------------
// Prepass: fp32 -> bf16 convert (row-major) + row norms.
// ws layout: norms[12288] | xbf[8192*256] | cbf[4096*256]
// ---------------------------------------------------------------------------
__global__ __launch_bounds__(256) void prep_kernel(const float* __restrict__ x,
                                                   const float* __restrict__ c,
                                                   float* __restrict__ norms,
                                                   unsigned short* __restrict__ xbf,
                                                   unsigned short* __restrict__ cbf) {
    const int t = threadIdx.x, lane = t & 63;
    const int wbase = (blockIdx.x * 4 + (t >> 6)) * 4;
    #pragma unroll
    for (int rr = 0; rr < 4; ++rr) {
        const int gw = wbase + rr;                        // 0..12287
        const float* src;
        unsigned short* dst;
        if (gw < NROWS) { src = x + (size_t)gw * DIM;           dst = xbf + (size_t)gw * DIM; }
        else            { src = c + (size_t)(gw - NROWS) * DIM; dst = cbf + (size_t)(gw - NROWS) * DIM; }
        float4 v = ((const float4*)src)[lane];
        ushort4 b;
        b.x = f2bf(v.x); b.y = f2bf(v.y); b.z = f2bf(v.z); b.w = f2bf(v.w);
        ((ushort4*)dst)[lane] = b;
        float s = v.x * v.x + v.y * v.y + v.z * v.z + v.w * v.w;
        #pragma unroll
        for (int m = 32; m; m >>= 1) s += __shfl_xor(s, m);
        if (lane == 0) norms[gw] = s;
    }
}

// ---------------------------------------------------------------------------
// Main kernel (R4): M-tile 128 x 2 N-tiles of 128, double-buffered LDS
// (2 x (8KB A + 8KB B) = 32 KB), 16-step software pipeline, ONE barrier per
// step with prefetch issued before compute -> stage(s+1) has a full compute
// phase to land before the vmcnt drain at the next barrier.
// Swizzle: chunk (16B) at physical pos p of row r holds logical chunk
// p ^ ((r>>1)&3) -> frag ds_read_b128 is 2-way bank aliasing (free, m136).
// Applied on the staging SOURCE address (global_load_lds dest is forced
// lane-contiguous, m104/m108).
// ---------------------------------------------------------------------------
__global__ __launch_bounds__(256) void rbf_mfma(const unsigned short* __restrict__ xbf,
                                                const unsigned short* __restrict__ cbf,
                                                const float* __restrict__ w,
                                                const float* __restrict__ sigp,
                                                const float* __restrict__ norms,
                                                float* __restrict__ out) {
    __shared__ __align__(16) short As[2][128 * 32];
    __shared__ __align__(16) short Bs[2][128 * 32];

    const int t    = threadIdx.x;
    const int wave = t >> 6, lane = t & 63;
    const int m0    = blockIdx.y * 128;
    const int nbase = blockIdx.x * 256;     // 2 n-tiles of 128
    const int wy = wave >> 1, wx = wave & 1;
    const int lr = lane & 15;               // frag m/n index
    const int g  = lane >> 4;               // frag k-group / row-quad

    // ---- staging assignment: wave stages rows 32w..32w+31, 2 issues each ----
    const int r_in = lane >> 2;                         // 0..15
    const int c_l  = (lane & 3) ^ ((r_in >> 1) & 3);    // logical chunk (swizzle)
    const unsigned short* gA0 = xbf + (size_t)(m0    + 32 * wave + r_in) * DIM + c_l * 8;
    const unsigned short* gB0 = cbf + (size_t)(nbase + 32 * wave + r_in) * DIM + c_l * 8;
    const int lbase = (32 * wave) * 32;     // short offset of wave's staging rows

    // ---- fragment read offsets (shorts, within one 8 KB buffer) ----
    int aoff[4], boff[4];
    #pragma unroll
    for (int i = 0; i < 4; ++i) {
        int r = 64 * wy + 16 * i + lr;
        aoff[i] = r * 32 + ((g ^ ((r >> 1) & 3)) * 8);
    }
    #pragma unroll
    for (int j = 0; j < 4; ++j) {
        int r = 64 * wx + 16 * j + lr;
        boff[j] = r * 32 + ((g ^ ((r >> 1) & 3)) * 8);
    }

    // ---- preload x-norms for this lane's 16 output rows ----
    f32x4 x2v[4];
    #pragma unroll
    for (int i = 0; i < 4; ++i)
        x2v[i] = *(const f32x4*)(norms + m0 + 64 * wy + 16 * i + 4 * g);
    const float sigma = sigp[0];

    f32x4 acc[4][4];
    #pragma unroll
    for (int i = 0; i < 4; ++i)
        #pragma unroll
        for (int j = 0; j < 4; ++j) acc[i][j] = f32x4{0, 0, 0, 0};
    float rs[4][4];   // [i][r] running phi-sums for this lane's rows
    #pragma unroll
    for (int i = 0; i < 4; ++i)
        #pragma unroll
        for (int r = 0; r < 4; ++r) rs[i][r] = 0.f;

    auto stage = [&](int s, int buf) {
        const int ko = (s & 7) * 32;                       // K offset (shorts)
        const int nt = s >> 3;                             // n-tile 0/1
        const unsigned short* a0 = gA0 + ko;
        const unsigned short* b0 = gB0 + (size_t)nt * 128 * DIM + ko;
        short* la = &As[buf][lbase];
        short* lb = &Bs[buf][lbase];
        __builtin_amdgcn_global_load_lds((const AS1 void*)a0,              (AS3 void*)la,         16, 0, 0);
        __builtin_amdgcn_global_load_lds((const AS1 void*)(a0 + 16 * DIM), (AS3 void*)(la + 512), 16, 0, 0);
        __builtin_amdgcn_global_load_lds((const AS1 void*)b0,              (AS3 void*)lb,         16, 0, 0);
        __builtin_amdgcn_global_load_lds((const AS1 void*)(b0 + 16 * DIM), (AS3 void*)(lb + 512), 16, 0, 0);
    };

    stage(0, 0);

    #pragma unroll
    for (int s = 0; s < 16; ++s) {
        __syncthreads();                      // drains stage(s); syncs compute(s-1)
        if (s < 15) stage(s + 1, (s + 1) & 1);   // prefetch: lands during compute(s)

        const short* cA = As[s & 1];
        const short* cB = Bs[s & 1];
        bf16x8 a[4], b[4];
        #pragma unroll
        for (int i = 0; i < 4; ++i) a[i] = *(const bf16x8*)(cA + aoff[i]);
        #pragma unroll
        for (int j = 0; j < 4; ++j) b[j] = *(const bf16x8*)(cB + boff[j]);
        #pragma unroll
        for (int i = 0; i < 4; ++i)
            #pragma unroll
            for (int j = 0; j < 4; ++j)
                acc[i][j] = __builtin_amdgcn_mfma_f32_16x16x32_bf16(a[i], b[j], acc[i][j], 0, 0, 0);

        if ((s & 7) == 7) {
            // ---- n-tile epilogue: accumulate w*exp(-sigma*d2) into rs ----
            const int nt = s >> 3;
            #pragma unroll
            for (int j = 0; j < 4; ++j) {
                const int n = nbase + nt * 128 + 64 * wx + 16 * j + lr;
                const float c2v = norms[NROWS + n];
                const float wv  = w[n];
                #pragma unroll
                for (int i = 0; i < 4; ++i)
                    #pragma unroll
                    for (int r = 0; r < 4; ++r) {
                        float d2 = x2v[i][r] + c2v - 2.0f * acc[i][j][r];
                        d2 = fmaxf(d2, 0.0f);
                        rs[i][r] += wv * __expf(-sigma * d2);
                    }
            }
            #pragma unroll
            for (int i = 0; i < 4; ++i)
                #pragma unroll
                for (int j = 0; j < 4; ++j) acc[i][j] = f32x4{0, 0, 0, 0};
        }
    }

    // ---- final: reduce rs over the 16 lr-lanes, one atomic per row ----
    #pragma unroll
    for (int i = 0; i < 4; ++i) {
        const int mbase = m0 + 64 * wy + 16 * i + 4 * g;
        #pragma unroll
        for (int r = 0; r < 4; ++r) {
            float v = rs[i][r];
            v += __shfl_xor(v, 1);
            v += __shfl_xor(v, 2);
            v += __shfl_xor(v, 4);
            v += __shfl_xor(v, 8);
            if (lr == 0) atomicAdd(&out[mbase + r], v);
        }
    }
}

// ---------------------------------------------------------------------------
// Fallback (R2 kernels) if ws is too small for the bf16 scratch copies.
// ---------------------------------------------------------------------------
__global__ __launch_bounds__(256) void norms_kernel(const float* __restrict__ x,
                                                    const float* __restrict__ c,
                                                    float* __restrict__ ws) {
    int t = threadIdx.x, lane = t & 63;
    int gw = blockIdx.x * 4 + (t >> 6);
    const float* src;
    float* dst;
    if (gw < NROWS) { src = x + (size_t)gw * DIM;           dst = ws + gw; }
    else            { src = c + (size_t)(gw - NROWS) * DIM; dst = ws + gw; }
    float4 v = ((const float4*)src)[lane];
    float s = v.x * v.x + v.y * v.y + v.z * v.z + v.w * v.w;
    #pragma unroll
    for (int m = 32; m; m >>= 1) s += __shfl_xor(s, m);
    if (lane == 0) *dst = s;
}

__global__ __launch_bounds__(256) void rbf_kernel(const float* __restrict__ x,
                                                  const float* __restrict__ cent,
                                                  const float* __restrict__ w,
                                                  const float* __restrict__ sigp,
                                                  const float* __restrict__ norms,
                                                  float* __restrict__ out) {
    __shared__ __align__(16) short xs[64 * 32];
    __shared__ __align__(16) short cs[64 * 32];
    const int t = threadIdx.x;
    const int m0 = blockIdx.y * 64, n0 = blockIdx.x * 64;
    const int srow = t >> 2, seg = t & 3;
    const int pchunk = seg ^ ((srow >> 1) & 3);
    const int sidx = srow * 32 + pchunk * 8;
    const float* xg = x    + (size_t)(m0 + srow) * DIM + seg * 8;
    const float* cg = cent + (size_t)(n0 + srow) * DIM + seg * 8;
    const int lane = t & 63, wave = t >> 6;
    const int lr = lane & 15, lg = lane >> 4;
    const int arow = 16 * wave + lr;
    const int aidx = arow * 32 + ((lg ^ ((arow >> 1) & 3)) * 8);
    f32x4 acc[4] = {f32x4{0,0,0,0}, f32x4{0,0,0,0}, f32x4{0,0,0,0}, f32x4{0,0,0,0}};
    for (int k0 = 0; k0 < DIM; k0 += 32) {
        float4 f0 = *(const float4*)(xg + k0);
        float4 f1 = *(const float4*)(xg + k0 + 4);
        float4 g0 = *(const float4*)(cg + k0);
        float4 g1 = *(const float4*)(cg + k0 + 4);
        __syncthreads();
        union { unsigned short s[8]; int4 v; } ux, uc;
        ux.s[0]=f2bf(f0.x); ux.s[1]=f2bf(f0.y); ux.s[2]=f2bf(f0.z); ux.s[3]=f2bf(f0.w);
        ux.s[4]=f2bf(f1.x); ux.s[5]=f2bf(f1.y); ux.s[6]=f2bf(f1.z); ux.s[7]=f2bf(f1.w);
        uc.s[0]=f2bf(g0.x); uc.s[1]=f2bf(g0.y); uc.s[2]=f2bf(g0.z); uc.s[3]=f2bf(g0.w);
        uc.s[4]=f2bf(g1.x); uc.s[5]=f2bf(g1.y); uc.s[6]=f2bf(g1.z); uc.s[7]=f2bf(g1.w);
        *(int4*)(xs + sidx) = ux.v;
        *(int4*)(cs + sidx) = uc.v;
        __syncthreads();
        bf16x8 a = *(const bf16x8*)(xs + aidx);
        #pragma unroll
        for (int bt = 0; bt < 4; ++bt) {
            const int brow = 16 * bt + lr;
            bf16x8 b = *(const bf16x8*)(cs + brow * 32 + ((lg ^ ((brow >> 1) & 3)) * 8));
            acc[bt] = __builtin_amdgcn_mfma_f32_16x16x32_bf16(a, b, acc[bt], 0, 0, 0);
        }
    }
    const float sigma = sigp[0];
    const float* x2 = norms;
    const float* c2 = norms + NROWS;
    const int rbase = m0 + 16 * wave + lg * 4;
    float x2v[4];
    #pragma unroll
    for (int r = 0; r < 4; ++r) x2v[r] = x2[rbase + r];
    float rs[4] = {0.f, 0.f, 0.f, 0.f};
    #pragma unroll
    for (int bt = 0; bt < 4; ++bt) {
        const int col = n0 + 16 * bt + lr;
        const float c2v = c2[col];
        const float wvv = w[col];
        #pragma unroll
        for (int r = 0; r < 4; ++r) {
            float d2 = x2v[r] + c2v - 2.0f * acc[bt][r];
            d2 = fmaxf(d2, 0.0f);
            rs[r] += wvv * __expf(-sigma * d2);
        }
    }
    #pragma unroll
    for (int r = 0; r < 4; ++r) {
        rs[r] += __shfl_xor(rs[r], 1);
        rs[r] += __shfl_xor(rs[r], 2);
        rs[r] += __shfl_xor(rs[r], 4);
        rs[r] += __shfl_xor(rs[r], 8);
    }
    if (lr == 0) {
        #pragma unroll
        for (int r = 0; r < 4; ++r) atomicAdd(&out[rbase + r], rs[r]);
    }
}

extern "C" void kernel_launch(void* const* d_in, const int* in_sizes, int n_in,
                              void* d_out, int out_size, void* d_ws, size_t ws_size,
                              hipStream_t stream) {
    const float* x    = (const float*)d_in[0];
    const float* cent = (const float*)d_in[1];
    const float* w    = (const float*)d_in[2];
    const float* sig  = (const float*)d_in[3];
    float* out = (float*)d_out;

    const size_t norms_elems = NROWS + NCENT;              // 12288 floats
    const size_t xbf_off  = norms_elems * sizeof(float);
    const size_t cbf_off  = xbf_off + (size_t)NROWS * DIM * sizeof(unsigned short);
    const size_t ws_need  = cbf_off + (size_t)NCENT * DIM * sizeof(unsigned short);

    hipMemsetAsync(d_out, 0, (size_t)out_size * sizeof(float), stream);

    if (ws_size >= ws_need) {
        float* norms = (float*)d_ws;
        unsigned short* xbf = (unsigned short*)((char*)d_ws + xbf_off);
        unsigned short* cbf = (unsigned short*)((char*)d_ws + cbf_off);
        prep_kernel<<<(NROWS + NCENT) / 16, 256, 0, stream>>>(x, cent, norms, xbf, cbf);
        rbf_mfma<<<dim3(NCENT / 256, NROWS / 128), 256, 0, stream>>>(xbf, cbf, w, sig, norms, out);
    } else {
        float* norms = (float*)d_ws;
        norms_kernel<<<(NROWS + NCENT) / 4, 256, 0, stream>>>(x, cent, norms);
        rbf_kernel<<<dim3(NCENT / 64, NROWS / 64), 256, 0, stream>>>(x, cent, w, sig, norms, out);
    }
}

// Round 5
// 106.775 us; speedup vs baseline: 1.0737x; 1.0737x over previous
//
#include <hip/hip_runtime.h>

#define NROWS 8192
#define NCENT 4096
#define DIM   256

#define AS1 __attribute__((address_space(1)))
#define AS3 __attribute__((address_space(3)))

typedef short bf16x8 __attribute__((ext_vector_type(8)));
typedef float f32x4  __attribute__((ext_vector_type(4)));

// fp32 -> bf16 round-to-nearest-even
__device__ inline unsigned short f2bf(float f) {
    unsigned u = __float_as_uint(f);
    return (unsigned short)((u + 0x7fffu + ((u >> 16) & 1u)) >> 16);
}

// ---------------------------------------------------------------------------
// Prepass: fp32 -> bf16 convert (row-major) + row norms.
// ws layout: norms[12288] | xbf[8192*256] | cbf[4096*256]
// ---------------------------------------------------------------------------
__global__ __launch_bounds__(256) void prep_kernel(const float* __restrict__ x,
                                                   const float* __restrict__ c,
                                                   float* __restrict__ norms,
                                                   unsigned short* __restrict__ xbf,
                                                   unsigned short* __restrict__ cbf) {
    const int t = threadIdx.x, lane = t & 63;
    const int wbase = (blockIdx.x * 4 + (t >> 6)) * 4;
    #pragma unroll
    for (int rr = 0; rr < 4; ++rr) {
        const int gw = wbase + rr;                        // 0..12287
        const float* src;
        unsigned short* dst;
        if (gw < NROWS) { src = x + (size_t)gw * DIM;           dst = xbf + (size_t)gw * DIM; }
        else            { src = c + (size_t)(gw - NROWS) * DIM; dst = cbf + (size_t)(gw - NROWS) * DIM; }
        float4 v = ((const float4*)src)[lane];
        ushort4 b;
        b.x = f2bf(v.x); b.y = f2bf(v.y); b.z = f2bf(v.z); b.w = f2bf(v.w);
        ((ushort4*)dst)[lane] = b;
        float s = v.x * v.x + v.y * v.y + v.z * v.z + v.w * v.w;
        #pragma unroll
        for (int m = 32; m; m >>= 1) s += __shfl_xor(s, m);
        if (lane == 0) norms[gw] = s;
    }
}

// ---------------------------------------------------------------------------
// Main kernel (R5): 128x128 tile, grid (32,64) = 2048 blocks (8/CU queued,
// R4's 1024-block grid tanked occupancy to 10%), double-buffered LDS with
// ONE barrier per step (prefetch s+1 issued before compute(s)), and an XCD
// swizzle so each XCD's stripe (8 m-tiles x all n) fits its 4 MB L2
// (A 512KB + B 2MB) -> staging loads are L2 hits.
// Swizzle: chunk (16B) at physical pos p of row r holds logical chunk
// p ^ ((r>>1)&3) -> frag ds_read_b128 is 2-way bank aliasing (free, m136);
// applied on the staging SOURCE address (global_load_lds dest is forced
// lane-contiguous, m104/m108).
// ---------------------------------------------------------------------------
__global__ __launch_bounds__(256) void rbf_mfma(const unsigned short* __restrict__ xbf,
                                                const unsigned short* __restrict__ cbf,
                                                const float* __restrict__ w,
                                                const float* __restrict__ sigp,
                                                const float* __restrict__ norms,
                                                float* __restrict__ out) {
    __shared__ __align__(16) short As[2][128 * 32];
    __shared__ __align__(16) short Bs[2][128 * 32];

    const int t    = threadIdx.x;
    const int wave = t >> 6, lane = t & 63;

    // ---- XCD-affinity remap: dispatch-linear id -> (bx', by') so each XCD
    //      (round-robin over dispatch order) gets an 8-m-tile x 32-n stripe ----
    const int lin = blockIdx.y * 32 + blockIdx.x;   // 0..2047, dispatch order
    const int xcd = lin & 7;
    const int pos = lin >> 3;                       // 0..255
    const int byp = (xcd << 3) + (pos >> 5);        // 0..63
    const int bxp = pos & 31;                       // 0..31
    const int m0  = byp * 128;
    const int n0  = bxp * 128;

    const int wy = wave >> 1, wx = wave & 1;
    const int lr = lane & 15;               // frag m/n index
    const int g  = lane >> 4;               // frag k-group / row-quad

    // ---- staging assignment: wave stages rows 32w..32w+31, 2 issues each ----
    const int r_in = lane >> 2;                         // 0..15
    const int c_l  = (lane & 3) ^ ((r_in >> 1) & 3);    // logical chunk (swizzle)
    const unsigned short* gA0 = xbf + (size_t)(m0 + 32 * wave + r_in) * DIM + c_l * 8;
    const unsigned short* gB0 = cbf + (size_t)(n0 + 32 * wave + r_in) * DIM + c_l * 8;
    const int lbase = (32 * wave) * 32;     // short offset of wave's staging rows

    // ---- fragment read offsets (shorts, within one 8 KB buffer) ----
    int aoff[4], boff[4];
    #pragma unroll
    for (int i = 0; i < 4; ++i) {
        int r = 64 * wy + 16 * i + lr;
        aoff[i] = r * 32 + ((g ^ ((r >> 1) & 3)) * 8);
    }
    #pragma unroll
    for (int j = 0; j < 4; ++j) {
        int r = 64 * wx + 16 * j + lr;
        boff[j] = r * 32 + ((g ^ ((r >> 1) & 3)) * 8);
    }

    f32x4 acc[4][4];
    #pragma unroll
    for (int i = 0; i < 4; ++i)
        #pragma unroll
        for (int j = 0; j < 4; ++j) acc[i][j] = f32x4{0, 0, 0, 0};

    auto stage = [&](int s, int buf) {
        const int ko = s * 32;               // K offset (shorts)
        const unsigned short* a0 = gA0 + ko;
        const unsigned short* b0 = gB0 + ko;
        short* la = &As[buf][lbase];
        short* lb = &Bs[buf][lbase];
        __builtin_amdgcn_global_load_lds((const AS1 void*)a0,              (AS3 void*)la,         16, 0, 0);
        __builtin_amdgcn_global_load_lds((const AS1 void*)(a0 + 16 * DIM), (AS3 void*)(la + 512), 16, 0, 0);
        __builtin_amdgcn_global_load_lds((const AS1 void*)b0,              (AS3 void*)lb,         16, 0, 0);
        __builtin_amdgcn_global_load_lds((const AS1 void*)(b0 + 16 * DIM), (AS3 void*)(lb + 512), 16, 0, 0);
    };

    stage(0, 0);

    #pragma unroll
    for (int s = 0; s < 8; ++s) {
        __syncthreads();                        // drains stage(s); syncs compute(s-1)
        if (s < 7) stage(s + 1, (s + 1) & 1);   // prefetch lands during compute(s)

        const short* cA = As[s & 1];
        const short* cB = Bs[s & 1];
        bf16x8 a[4], b[4];
        #pragma unroll
        for (int i = 0; i < 4; ++i) a[i] = *(const bf16x8*)(cA + aoff[i]);
        #pragma unroll
        for (int j = 0; j < 4; ++j) b[j] = *(const bf16x8*)(cB + boff[j]);
        #pragma unroll
        for (int i = 0; i < 4; ++i)
            #pragma unroll
            for (int j = 0; j < 4; ++j)
                acc[i][j] = __builtin_amdgcn_mfma_f32_16x16x32_bf16(a[i], b[j], acc[i][j], 0, 0, 0);
    }

    // ---- epilogue: phi = w*exp(-sigma*max(d2,0)); reduce 64 cols per row ----
    const float sigma = sigp[0];
    float c2v[4], wv[4];
    #pragma unroll
    for (int j = 0; j < 4; ++j) {
        int n = n0 + 64 * wx + 16 * j + lr;
        c2v[j] = norms[NROWS + n];
        wv[j]  = w[n];
    }

    #pragma unroll
    for (int i = 0; i < 4; ++i) {
        const int mbase = m0 + 64 * wy + 16 * i + 4 * g;   // 4 consecutive rows
        float4 x2v = *(const float4*)(norms + mbase);
        float rs[4] = {0.f, 0.f, 0.f, 0.f};
        #pragma unroll
        for (int j = 0; j < 4; ++j) {
            #pragma unroll
            for (int r = 0; r < 4; ++r) {
                float x2r = (r == 0) ? x2v.x : (r == 1) ? x2v.y : (r == 2) ? x2v.z : x2v.w;
                float d2 = x2r + c2v[j] - 2.0f * acc[i][j][r];
                d2 = fmaxf(d2, 0.0f);
                rs[r] += wv[j] * __expf(-sigma * d2);
            }
        }
        #pragma unroll
        for (int r = 0; r < 4; ++r) {
            rs[r] += __shfl_xor(rs[r], 1);
            rs[r] += __shfl_xor(rs[r], 2);
            rs[r] += __shfl_xor(rs[r], 4);
            rs[r] += __shfl_xor(rs[r], 8);
        }
        if (lr == 0) {
            #pragma unroll
            for (int r = 0; r < 4; ++r) atomicAdd(&out[mbase + r], rs[r]);
        }
    }
}

// ---------------------------------------------------------------------------
// Fallback (R2 kernels) if ws is too small for the bf16 scratch copies.
// ---------------------------------------------------------------------------
__global__ __launch_bounds__(256) void norms_kernel(const float* __restrict__ x,
                                                    const float* __restrict__ c,
                                                    float* __restrict__ ws) {
    int t = threadIdx.x, lane = t & 63;
    int gw = blockIdx.x * 4 + (t >> 6);
    const float* src;
    float* dst;
    if (gw < NROWS) { src = x + (size_t)gw * DIM;           dst = ws + gw; }
    else            { src = c + (size_t)(gw - NROWS) * DIM; dst = ws + gw; }
    float4 v = ((const float4*)src)[lane];
    float s = v.x * v.x + v.y * v.y + v.z * v.z + v.w * v.w;
    #pragma unroll
    for (int m = 32; m; m >>= 1) s += __shfl_xor(s, m);
    if (lane == 0) *dst = s;
}

__global__ __launch_bounds__(256) void rbf_kernel(const float* __restrict__ x,
                                                  const float* __restrict__ cent,
                                                  const float* __restrict__ w,
                                                  const float* __restrict__ sigp,
                                                  const float* __restrict__ norms,
                                                  float* __restrict__ out) {
    __shared__ __align__(16) short xs[64 * 32];
    __shared__ __align__(16) short cs[64 * 32];
    const int t = threadIdx.x;
    const int m0 = blockIdx.y * 64, n0 = blockIdx.x * 64;
    const int srow = t >> 2, seg = t & 3;
    const int pchunk = seg ^ ((srow >> 1) & 3);
    const int sidx = srow * 32 + pchunk * 8;
    const float* xg = x    + (size_t)(m0 + srow) * DIM + seg * 8;
    const float* cg = cent + (size_t)(n0 + srow) * DIM + seg * 8;
    const int lane = t & 63, wave = t >> 6;
    const int lr = lane & 15, lg = lane >> 4;
    const int arow = 16 * wave + lr;
    const int aidx = arow * 32 + ((lg ^ ((arow >> 1) & 3)) * 8);
    f32x4 acc[4] = {f32x4{0,0,0,0}, f32x4{0,0,0,0}, f32x4{0,0,0,0}, f32x4{0,0,0,0}};
    for (int k0 = 0; k0 < DIM; k0 += 32) {
        float4 f0 = *(const float4*)(xg + k0);
        float4 f1 = *(const float4*)(xg + k0 + 4);
        float4 g0 = *(const float4*)(cg + k0);
        float4 g1 = *(const float4*)(cg + k0 + 4);
        __syncthreads();
        union { unsigned short s[8]; int4 v; } ux, uc;
        ux.s[0]=f2bf(f0.x); ux.s[1]=f2bf(f0.y); ux.s[2]=f2bf(f0.z); ux.s[3]=f2bf(f0.w);
        ux.s[4]=f2bf(f1.x); ux.s[5]=f2bf(f1.y); ux.s[6]=f2bf(f1.z); ux.s[7]=f2bf(f1.w);
        uc.s[0]=f2bf(g0.x); uc.s[1]=f2bf(g0.y); uc.s[2]=f2bf(g0.z); uc.s[3]=f2bf(g0.w);
        uc.s[4]=f2bf(g1.x); uc.s[5]=f2bf(g1.y); uc.s[6]=f2bf(g1.z); uc.s[7]=f2bf(g1.w);
        *(int4*)(xs + sidx) = ux.v;
        *(int4*)(cs + sidx) = uc.v;
        __syncthreads();
        bf16x8 a = *(const bf16x8*)(xs + aidx);
        #pragma unroll
        for (int bt = 0; bt < 4; ++bt) {
            const int brow = 16 * bt + lr;
            bf16x8 b = *(const bf16x8*)(cs + brow * 32 + ((lg ^ ((brow >> 1) & 3)) * 8));
            acc[bt] = __builtin_amdgcn_mfma_f32_16x16x32_bf16(a, b, acc[bt], 0, 0, 0);
        }
    }
    const float sigma = sigp[0];
    const float* x2 = norms;
    const float* c2 = norms + NROWS;
    const int rbase = m0 + 16 * wave + lg * 4;
    float x2v[4];
    #pragma unroll
    for (int r = 0; r < 4; ++r) x2v[r] = x2[rbase + r];
    float rs[4] = {0.f, 0.f, 0.f, 0.f};
    #pragma unroll
    for (int bt = 0; bt < 4; ++bt) {
        const int col = n0 + 16 * bt + lr;
        const float c2v = c2[col];
        const float wvv = w[col];
        #pragma unroll
        for (int r = 0; r < 4; ++r) {
            float d2 = x2v[r] + c2v - 2.0f * acc[bt][r];
            d2 = fmaxf(d2, 0.0f);
            rs[r] += wvv * __expf(-sigma * d2);
        }
    }
    #pragma unroll
    for (int r = 0; r < 4; ++r) {
        rs[r] += __shfl_xor(rs[r], 1);
        rs[r] += __shfl_xor(rs[r], 2);
        rs[r] += __shfl_xor(rs[r], 4);
        rs[r] += __shfl_xor(rs[r], 8);
    }
    if (lr == 0) {
        #pragma unroll
        for (int r = 0; r < 4; ++r) atomicAdd(&out[rbase + r], rs[r]);
    }
}

extern "C" void kernel_launch(void* const* d_in, const int* in_sizes, int n_in,
                              void* d_out, int out_size, void* d_ws, size_t ws_size,
                              hipStream_t stream) {
    const float* x    = (const float*)d_in[0];
    const float* cent = (const float*)d_in[1];
    const float* w    = (const float*)d_in[2];
    const float* sig  = (const float*)d_in[3];
    float* out = (float*)d_out;

    const size_t norms_elems = NROWS + NCENT;              // 12288 floats
    const size_t xbf_off  = norms_elems * sizeof(float);
    const size_t cbf_off  = xbf_off + (size_t)NROWS * DIM * sizeof(unsigned short);
    const size_t ws_need  = cbf_off + (size_t)NCENT * DIM * sizeof(unsigned short);

    hipMemsetAsync(d_out, 0, (size_t)out_size * sizeof(float), stream);

    if (ws_size >= ws_need) {
        float* norms = (float*)d_ws;
        unsigned short* xbf = (unsigned short*)((char*)d_ws + xbf_off);
        unsigned short* cbf = (unsigned short*)((char*)d_ws + cbf_off);
        prep_kernel<<<(NROWS + NCENT) / 16, 256, 0, stream>>>(x, cent, norms, xbf, cbf);
        rbf_mfma<<<dim3(NCENT / 128, NROWS / 128), 256, 0, stream>>>(xbf, cbf, w, sig, norms, out);
    } else {
        float* norms = (float*)d_ws;
        norms_kernel<<<(NROWS + NCENT) / 4, 256, 0, stream>>>(x, cent, norms);
        rbf_kernel<<<dim3(NCENT / 64, NROWS / 64), 256, 0, stream>>>(x, cent, w, sig, norms, out);
    }
}